// Round 10
// baseline (262.597 us; speedup 1.0000x reference)
//
#include <hip/hip_runtime.h>
#include <hip/hip_bf16.h>

#define B_   2048
#define L_   200
#define DM_  512
#define HID_ 256
#define V_   40000
#define NPAD 40064          // 313 * 128 (WT padded rows; only 40000 used now)
#define LN_EPS 1e-5f

typedef short bf16x8 __attribute__((ext_vector_type(8)));
typedef float f32x4  __attribute__((ext_vector_type(4)));

// ---------------------------------------------------------------------------
// Kernel 1: W2 (f32, [256][40000]) -> WT (bf16, [NPAD][256])  (unchanged)
// ---------------------------------------------------------------------------
__global__ __launch_bounds__(256) void transpose_w2(const float* __restrict__ W2,
                                                    __hip_bfloat16* __restrict__ WT) {
    __shared__ float tile[64][65];
    const int n0 = blockIdx.x * 64;
    const int k0 = blockIdx.y * 64;
    const int tid = threadIdx.x;

    const int c = tid & 63, r4 = tid >> 6;
#pragma unroll
    for (int p = 0; p < 16; ++p) {
        int r = p * 4 + r4;
        int n = n0 + c;
        tile[r][c] = (n < V_) ? W2[(size_t)(k0 + r) * V_ + n] : 0.f;
    }
    __syncthreads();

    const int nl = tid >> 3;
    const int kb = (tid & 7) * 8;
#pragma unroll
    for (int p = 0; p < 2; ++p) {
        int n = p * 32 + nl;
        bf16x8 v;
#pragma unroll
        for (int j = 0; j < 8; ++j) {
            __hip_bfloat16 h = __float2bfloat16(tile[kb + j][n]);
            v[j] = *(short*)&h;
        }
        *(bf16x8*)(WT + (size_t)(n0 + n) * HID_ + k0 + kb) = v;
    }
}

// ---------------------------------------------------------------------------
// Kernel 2: head (unchanged)
// ---------------------------------------------------------------------------
__global__ __launch_bounds__(512) void head_kernel(const float* __restrict__ hidden,
                                                   const float* __restrict__ W1,
                                                   const float* __restrict__ b1,
                                                   const float* __restrict__ gamma,
                                                   const float* __restrict__ beta,
                                                   __hip_bfloat16* __restrict__ hout) {
    __shared__ float hid[8][DM_];
    __shared__ float part[8][HID_];
    __shared__ float red[2][8][4];
    const int r0 = blockIdx.x * 8;
    const int tid = threadIdx.x;
    const int col = tid & 255, half = tid >> 8;

    {
        const float4* src = (const float4*)(hidden + (size_t)r0 * DM_);
        float4* dst = (float4*)(&hid[0][0]);
        for (int i = tid; i < 8 * DM_ / 4; i += 512) dst[i] = src[i];
    }
    __syncthreads();

    float acc[8] = {0.f, 0.f, 0.f, 0.f, 0.f, 0.f, 0.f, 0.f};
    const int kbeg = half * (DM_ / 2);
#pragma unroll 8
    for (int k = kbeg; k < kbeg + DM_ / 2; ++k) {
        float w = W1[(size_t)k * HID_ + col];
#pragma unroll
        for (int r = 0; r < 8; ++r) acc[r] = fmaf(hid[r][k], w, acc[r]);
    }

    if (half == 1) {
#pragma unroll
        for (int r = 0; r < 8; ++r) part[r][col] = acc[r];
    }
    __syncthreads();
    if (half == 0) {
        const float b1v = b1[col], gv = gamma[col], bev = beta[col];
        const int lane = col & 63, wv = col >> 6;
        float v[8];
#pragma unroll
        for (int r = 0; r < 8; ++r) {
            v[r] = acc[r] + part[r][col] + b1v;
            float s = v[r], q = v[r] * v[r];
#pragma unroll
            for (int off = 1; off < 64; off <<= 1) {
                s += __shfl_xor(s, off);
                q += __shfl_xor(q, off);
            }
            if (lane == 0) { red[0][r][wv] = s; red[1][r][wv] = q; }
        }
        __syncthreads();
#pragma unroll
        for (int r = 0; r < 8; ++r) {
            float s  = red[0][r][0] + red[0][r][1] + red[0][r][2] + red[0][r][3];
            float q  = red[1][r][0] + red[1][r][1] + red[1][r][2] + red[1][r][3];
            float mu = s * (1.f / HID_);
            float var = q * (1.f / HID_) - mu * mu;
            float hn = (v[r] - mu) * rsqrtf(var + LN_EPS) * gv + bev;
            float g  = 0.5f * hn * (1.f + erff(hn * 0.70710678118654752f));
            hout[(size_t)(r0 + r) * HID_ + col] = __float2bfloat16(g);
        }
    }
}

// ---------------------------------------------------------------------------
// Kernel 3: ROW-BAND GEMM. Block = 32 rows x quarter-V (10000 cols).
// 64 row-bands x 4 col-quarters = 256 blocks. No LDS: A in registers,
// B streamed L2->reg double-buffered. Each wave sweeps a contiguous col
// span 16 cols/step -> per-row forward-marching sequential write streams.
// ---------------------------------------------------------------------------
__global__ __launch_bounds__(256, 1) void gemm_kernel(const __hip_bfloat16* __restrict__ hA,
                                                      const __hip_bfloat16* __restrict__ BT,
                                                      const float* __restrict__ b2,
                                                      const float* __restrict__ lsp,
                                                      float* __restrict__ out) {
    // block id -> (col-quarter cq, row-band rt); xcd = b&7 = 2*cq + rt/32
    const int b = blockIdx.x;
    const int x = b & 7;
    const int i = b >> 3;                 // 0..31
    const int cq = x >> 1;                // 0..3
    const int rt = ((x & 1) << 5) + i;    // 0..63
    const int r0 = rt * 32;

    const int lane = threadIdx.x & 63;
    const int wv = threadIdx.x >> 6;
    const float ls = lsp[0];

    const int rlo  = lane & 15;           // fragment row (and B-col) index
    const int koff = (lane >> 4) << 3;    // k element offset (8 elems = 16B)
    const int c4   = (lane >> 4) << 2;    // output col sub-offset

    // A fragments for the whole block: 2 row-groups x 8 k-slices, 64 VGPR
    bf16x8 af[2][8];
#pragma unroll
    for (int g = 0; g < 2; ++g)
#pragma unroll
        for (int ks = 0; ks < 8; ++ks)
            af[g][ks] = *(const bf16x8*)(hA + (size_t)(r0 + 16 * g + rlo) * HID_
                                             + ks * 32 + koff);

    // wave's contiguous chunk range (chunk = 16 cols); quarter = 625 chunks
    const int qbase = cq * 625;
    const int cbeg = qbase + ((wv == 0) ? 0 : 157 + (wv - 1) * 156);
    const int cend = qbase + ((wv == 0) ? 157 : 157 + wv * 156);

    float* outw = out + (size_t)(r0 + rlo) * V_;
    const size_t rowstep = (size_t)16 * V_;

#define LOADB(bq, bv, c)                                                      \
    {                                                                         \
        const int col0 = (c) * 16;                                            \
        _Pragma("unroll")                                                     \
        for (int ks = 0; ks < 8; ++ks)                                        \
            bq[ks] = *(const bf16x8*)(BT + (size_t)(col0 + rlo) * HID_        \
                                          + ks * 32 + koff);                  \
        bv = *(const f32x4*)(b2 + col0 + c4);                                 \
    }

#define COMPUTE_STORE(bq, bv, c)                                              \
    {                                                                         \
        f32x4 a0 = (f32x4){0.f, 0.f, 0.f, 0.f};                               \
        f32x4 a1 = (f32x4){0.f, 0.f, 0.f, 0.f};                               \
        _Pragma("unroll")                                                     \
        for (int ks = 0; ks < 8; ++ks) {                                      \
            a0 = __builtin_amdgcn_mfma_f32_16x16x32_bf16(bq[ks], af[0][ks],   \
                                                         a0, 0, 0, 0);        \
            a1 = __builtin_amdgcn_mfma_f32_16x16x32_bf16(bq[ks], af[1][ks],   \
                                                         a1, 0, 0, 0);        \
        }                                                                     \
        const int col = (c) * 16 + c4;                                        \
        *(f32x4*)(outw + col)           = (a0 + bv) * ls;                     \
        *(f32x4*)(outw + rowstep + col) = (a1 + bv) * ls;                     \
    }

    bf16x8 bq0[8], bq1[8];
    f32x4 bv0, bv1;
    LOADB(bq0, bv0, cbeg);
    int c = cbeg;
    for (; c + 2 <= cend; c += 2) {
        LOADB(bq1, bv1, c + 1);
        COMPUTE_STORE(bq0, bv0, c);
        if (c + 2 < cend) LOADB(bq0, bv0, c + 2);
        COMPUTE_STORE(bq1, bv1, c + 1);
    }
    if (c < cend) COMPUTE_STORE(bq0, bv0, c);
#undef LOADB
#undef COMPUTE_STORE
}

// ---------------------------------------------------------------------------
// Kernel 4: history scatter (unchanged)
// ---------------------------------------------------------------------------
__global__ __launch_bounds__(256) void hist_kernel(const int* __restrict__ loc,
                                                   const int* __restrict__ mask,
                                                   const float* __restrict__ rw,
                                                   const float* __restrict__ fw,
                                                   const float* __restrict__ hs,
                                                   float* __restrict__ out) {
    const int idx = blockIdx.x * 256 + threadIdx.x;
    if (idx >= B_ * L_) return;
    const int b = idx / L_, t = idx - b * L_;
    if (mask[idx] != 0) {
        float recency = expf(-0.1f * (float)(L_ - 1 - t)) * rw[0];
        float val = (recency + fw[0]) * hs[0];
        atomicAdd(out + (size_t)b * V_ + loc[idx], val);
    }
}

// ---------------------------------------------------------------------------
extern "C" void kernel_launch(void* const* d_in, const int* in_sizes, int n_in,
                              void* d_out, int out_size, void* d_ws, size_t ws_size,
                              hipStream_t stream) {
    const float* hidden = (const float*)d_in[0];
    const int*   loc    = (const int*)d_in[1];
    const int*   mask   = (const int*)d_in[2];
    const float* W1     = (const float*)d_in[3];
    const float* b1     = (const float*)d_in[4];
    const float* gamma  = (const float*)d_in[5];
    const float* beta   = (const float*)d_in[6];
    const float* W2     = (const float*)d_in[7];
    const float* b2     = (const float*)d_in[8];
    const float* rw     = (const float*)d_in[9];
    const float* fw     = (const float*)d_in[10];
    const float* hs     = (const float*)d_in[11];
    const float* ls     = (const float*)d_in[12];
    float* out = (float*)d_out;

    __hip_bfloat16* WT   = (__hip_bfloat16*)d_ws;                       // NPAD*256*2
    __hip_bfloat16* hbuf = (__hip_bfloat16*)((char*)d_ws + 20512768);   // 2048*256*2

    transpose_w2<<<dim3(NPAD / 64, HID_ / 64), 256, 0, stream>>>(W2, WT);
    head_kernel<<<B_ / 8, 512, 0, stream>>>(hidden, W1, b1, gamma, beta, hbuf);
    gemm_kernel<<<256, 256, 0, stream>>>(hbuf, WT, b2, ls, out);
    hist_kernel<<<(B_ * L_ + 255) / 256, 256, 0, stream>>>(loc, mask, rw, fw, hs, out);
}